// Round 11
// baseline (385.273 us; speedup 1.0000x reference)
//
#include <hip/hip_runtime.h>

// GcnEncoderGraph multi-kernel pipeline. B=8, N=2048, DIN=32, DH=DE=64, R=3.
// R11 = R10 (356us) with dispatch-count cuts:
//  - gemm1 packs `rel` inline via __ballot (lane reads col j*64+lane: 64x4B
//    fully coalesced -> one ballot = one 64-col mask row). R9's inline pack
//    failed because its lanes sat at 1KB stride (64 cache lines/instr).
//    PLANES buffer + pack dispatch deleted; UP written from LDS.
//  - tail merged into gemm3 via last-arriver (R9-proven protocol; dirty L2
//    at that point is only ~64KB so the fence is cheap). CNT zeroed by xw1.
// Journal: no in-kernel all-block rendezvous (R4/R8); no per-phase device
// fences (R8/R9); TLP >= 8 waves/CU for gemms; dispatch boundary = cheap sync.

#define NN 2048

typedef short short8 __attribute__((ext_vector_type(8)));
typedef float floatx4 __attribute__((ext_vector_type(4)));

__device__ __forceinline__ unsigned short f2bf(float x) {
  unsigned u = __float_as_uint(x);
  u += 0x7FFFu + ((u >> 16) & 1u);
  return (unsigned short)(u >> 16);
}

// ---------- shared epilogue: combine 8 waves, bias + L2norm (+relu/+pool) ----
template <bool RELU, bool POOL3>
__device__ __forceinline__ void gemm_epilogue(
    floatx4 acc[4][4], char* scratch, const float* __restrict__ bias,
    float* __restrict__ Hout, float* __restrict__ part3, int b, int it) {
  const int tid = threadIdx.x;
  const int wave = tid >> 6, lane = tid & 63;
  const int m = lane & 15, kq = lane >> 4;
  const int i0 = it * 64;
  floatx4* cb = (floatx4*)scratch;
  for (int k = 7; k >= 1; --k) {
    if (wave == k) {
      if (k == 7) {
#pragma unroll
        for (int rs = 0; rs < 4; ++rs)
#pragma unroll
          for (int t = 0; t < 4; ++t) cb[(rs * 4 + t) * 64 + lane] = acc[rs][t];
      } else {
#pragma unroll
        for (int rs = 0; rs < 4; ++rs)
#pragma unroll
          for (int t = 0; t < 4; ++t) {
            floatx4 v = cb[(rs * 4 + t) * 64 + lane];
            cb[(rs * 4 + t) * 64 + lane] = v + acc[rs][t];
          }
      }
    }
    __syncthreads();
  }
  if (wave == 0) {
#pragma unroll
    for (int rs = 0; rs < 4; ++rs)
#pragma unroll
      for (int t = 0; t < 4; ++t) acc[rs][t] += cb[(rs * 4 + t) * 64 + lane];
    float bv[4];
#pragma unroll
    for (int t = 0; t < 4; ++t) bv[t] = bias[t * 16 + m];
    float pmt[4] = {-3.4e38f, -3.4e38f, -3.4e38f, -3.4e38f};
#pragma unroll
    for (int rs = 0; rs < 4; ++rs) {
      float ss[4];
#pragma unroll
      for (int reg = 0; reg < 4; ++reg) {
#pragma unroll
        for (int t = 0; t < 4; ++t) acc[rs][t][reg] += bv[t];
        ss[reg] = acc[rs][0][reg] * acc[rs][0][reg] +
                  acc[rs][1][reg] * acc[rs][1][reg] +
                  acc[rs][2][reg] * acc[rs][2][reg] +
                  acc[rs][3][reg] * acc[rs][3][reg];
#pragma unroll
        for (int off = 1; off <= 8; off <<= 1)
          ss[reg] += __shfl_xor(ss[reg], off);
        ss[reg] = 1.0f / fmaxf(sqrtf(ss[reg]), 1e-12f);
      }
#pragma unroll
      for (int t = 0; t < 4; ++t) {
#pragma unroll
        for (int reg = 0; reg < 4; ++reg) {
          float o = acc[rs][t][reg] * ss[reg];
          if (RELU) o = fmaxf(o, 0.0f);
          if (POOL3)
            pmt[t] = fmaxf(pmt[t], o);
          else
            Hout[((long)b * NN + i0 + rs * 16 + kq * 4 + reg) * 64 + t * 16 + m] = o;
        }
      }
    }
    if (POOL3) {
#pragma unroll
      for (int t = 0; t < 4; ++t) {
        pmt[t] = fmaxf(pmt[t], __shfl_xor(pmt[t], 16));
        pmt[t] = fmaxf(pmt[t], __shfl_xor(pmt[t], 32));
      }
      if (kq == 0) {
#pragma unroll
        for (int t = 0; t < 4; ++t)
          part3[((long)b * 32 + it) * 64 + t * 16 + m] = pmt[t];
      }
    }
  }
}

// ---------- mask word -> bf16x8 A-fragment (u24-multiply expand, R10) --------
__device__ __forceinline__ short8 expand_frag(unsigned word, int kq) {
  unsigned byte = (word >> (kq * 8)) & 0xffu;
  unsigned pp = byte | (byte << 15);
  union {
    unsigned uu[4];
    short8 s8;
  } fr;
  fr.uu[0] = (pp & 0x00010001u) * 0x3F80u;
  fr.uu[1] = (pp & 0x00040004u) * 0x0FE0u;
  fr.uu[2] = (pp & 0x00100010u) * 0x03F8u;
  fr.uu[3] = (pp & 0x00400040u) * 0x00FEu;
  return fr.s8;
}

// ---------- k_xw1: XW layer1 (R10 dev_xw_first) + CNT zero -------------------
__global__ __launch_bounds__(256) void k_xw1(const float* __restrict__ x,
                                             const float* __restrict__ w,
                                             unsigned short* __restrict__ xws,
                                             unsigned* __restrict__ CNT) {
  __shared__ __align__(16) char smemc[16640];
  const int u = blockIdx.x, tid = threadIdx.x;
  if (u == 0 && tid == 0) CNT[0] = 0;  // consumed by k_g3, 4 dispatches later
  float* xs = (float*)smemc;                   // [64][33]
  float* wsh = (float*)(smemc + 64 * 33 * 4);  // [32][64]
  const int jc = u & 31, b = (u >> 5) & 7, r = u >> 8;
  const int j0 = jc * 64;
  for (int idx = tid; idx < 64 * 32; idx += 256) {
    int row = idx >> 5, f = idx & 31;
    xs[row * 33 + f] = x[((long)b * NN + j0 + row) * 32 + f];
    wsh[idx] = w[r * 2048 + idx];
  }
  __syncthreads();
  const int j = tid & 63, g = tid >> 6;
  const int k = j0 + j;
  const int kblk = k >> 5, kq = (k >> 3) & 3, kj = k & 7;
  unsigned short* dst =
      xws + (((long)(r * 8 + b) * 64 + kblk) * 4 + g) * 512 + kj;
  float xr[32];
#pragma unroll
  for (int f = 0; f < 32; ++f) xr[f] = xs[j * 33 + f];
#pragma unroll
  for (int ii = 0; ii < 16; ++ii) {
    float acc = 0.f;
#pragma unroll
    for (int f = 0; f < 32; ++f) acc += xr[f] * wsh[f * 64 + g * 16 + ii];
    dst[(kq * 16 + ii) * 8] = f2bf(acc);
  }
}

// ---------- k_g1: ballot-pack rel -> LDS masks + UP; gemm<3>; epilogue -------
// grid 256: b = bid&7, it = bid>>3. Block 512 = 8 waves. LDS: 3x16KB masks
// (word w of row at row*64 + (w^(row&31))), combine buffer overlays plane 0.
__global__ __launch_bounds__(512) void k_g1(
    const int* __restrict__ rel, unsigned* __restrict__ UP,
    const unsigned short* __restrict__ xws, const float* __restrict__ bias,
    float* __restrict__ Hout) {
  __shared__ __align__(16) unsigned mw[3 * 4096];
  const int bid = blockIdx.x, tid = threadIdx.x;
  const int b = bid & 7, it = bid >> 3;
  const int wave = tid >> 6, lane = tid & 63;
  const int i0 = it * 64;

  // ---- pack: lane reads col j*64+lane (64x4B coalesced), ballot -> mask row
  for (int rr = 0; rr < 8; ++rr) {
    const int row = wave * 8 + rr;
    const int rsw = row & 31;
    const long rbase = ((long)b * NN + i0 + row) * NN;
    for (int jb = 0; jb < 4; ++jb) {
      int vv[8];
#pragma unroll
      for (int u = 0; u < 8; ++u)
        vv[u] = rel[rbase + (jb * 8 + u) * 64 + lane];
#pragma unroll
      for (int u = 0; u < 8; ++u) {
        const int j = jb * 8 + u;
        unsigned long long B1 = __ballot(vv[u] == 1);
        unsigned long long B2 = __ballot(vv[u] == 2);
        unsigned long long B3 = __ballot(vv[u] == 3);
        if (lane == 0) {
          const int o0 = row * 64 + ((2 * j) ^ rsw);
          const int o1 = row * 64 + ((2 * j + 1) ^ rsw);
          mw[o0] = (unsigned)B1;
          mw[o1] = (unsigned)(B1 >> 32);
          mw[4096 + o0] = (unsigned)B2;
          mw[4096 + o1] = (unsigned)(B2 >> 32);
          mw[8192 + o0] = (unsigned)B3;
          mw[8192 + o1] = (unsigned)(B3 >> 32);
        }
      }
    }
  }
  __syncthreads();
  // ---- UP = union plane, coalesced copy-out from LDS
  for (int idx = tid; idx < 4096; idx += 512) {
    int row = idx >> 6, w = idx & 63, sw = w ^ (row & 31);
    unsigned uu = mw[row * 64 + sw] | mw[4096 + row * 64 + sw] |
                  mw[8192 + row * 64 + sw];
    UP[((long)b * NN + i0 + row) * 64 + w] = uu;
  }

  // ---- gemm: 8 waves interleave K (kblk = kk8*8+wave), full K from LDS
  const int m = lane & 15, kq = lane >> 4;
  floatx4 acc[4][4];
#pragma unroll
  for (int rs = 0; rs < 4; ++rs)
#pragma unroll
    for (int t = 0; t < 4; ++t) acc[rs][t] = floatx4{0, 0, 0, 0};

  for (int kk8 = 0; kk8 < 8; ++kk8) {
    const int kblk = kk8 * 8 + wave;
#pragma unroll
    for (int p = 0; p < 3; ++p) {
      const unsigned short* bb =
          xws + ((long)(p * 8 + b) * 64 + kblk) * 2048 + lane * 8;
      short8 bf0 = *(const short8*)(bb);
      short8 bf1 = *(const short8*)(bb + 512);
      short8 bf2 = *(const short8*)(bb + 1024);
      short8 bf3 = *(const short8*)(bb + 1536);
#pragma unroll
      for (int rs = 0; rs < 4; ++rs) {
        const int row = rs * 16 + m;
        short8 af = expand_frag(mw[p * 4096 + row * 64 + (kblk ^ (row & 31))], kq);
        acc[rs][0] = __builtin_amdgcn_mfma_f32_16x16x32_bf16(af, bf0, acc[rs][0], 0, 0, 0);
        acc[rs][1] = __builtin_amdgcn_mfma_f32_16x16x32_bf16(af, bf1, acc[rs][1], 0, 0, 0);
        acc[rs][2] = __builtin_amdgcn_mfma_f32_16x16x32_bf16(af, bf2, acc[rs][2], 0, 0, 0);
        acc[rs][3] = __builtin_amdgcn_mfma_f32_16x16x32_bf16(af, bf3, acc[rs][3], 0, 0, 0);
      }
    }
  }
  __syncthreads();  // masks dead; LDS becomes combine buffer
  gemm_epilogue<true, false>(acc, (char*)mw, bias, Hout, nullptr, b, it);
}

// ---------- k_gemm2: union-plane gemm (R10 k_gemm8<1,true,false>) ------------
__global__ __launch_bounds__(512) void k_gemm2(
    const unsigned* __restrict__ UP, const unsigned short* __restrict__ xws,
    const float* __restrict__ bias, float* __restrict__ Hout) {
  __shared__ __align__(16) unsigned mw[4096];
  const int bid = blockIdx.x, tid = threadIdx.x;
  const int b = bid & 7, it = bid >> 3;
  const int wave = tid >> 6, lane = tid & 63;
  const int m = lane & 15, kq = lane >> 4;
  const int i0 = it * 64;
  for (int idx = tid; idx < 4096; idx += 512) {
    int row = idx >> 6, w = idx & 63;
    mw[row * 64 + (w ^ (row & 31))] = UP[((long)b * NN + i0 + row) * 64 + w];
  }
  __syncthreads();
  floatx4 acc[4][4];
#pragma unroll
  for (int rs = 0; rs < 4; ++rs)
#pragma unroll
    for (int t = 0; t < 4; ++t) acc[rs][t] = floatx4{0, 0, 0, 0};
  for (int kk8 = 0; kk8 < 8; ++kk8) {
    const int kblk = kk8 * 8 + wave;
    const unsigned short* bb = xws + ((long)b * 64 + kblk) * 2048 + lane * 8;
    short8 bf0 = *(const short8*)(bb);
    short8 bf1 = *(const short8*)(bb + 512);
    short8 bf2 = *(const short8*)(bb + 1024);
    short8 bf3 = *(const short8*)(bb + 1536);
#pragma unroll
    for (int rs = 0; rs < 4; ++rs) {
      const int row = rs * 16 + m;
      short8 af = expand_frag(mw[row * 64 + (kblk ^ (row & 31))], kq);
      acc[rs][0] = __builtin_amdgcn_mfma_f32_16x16x32_bf16(af, bf0, acc[rs][0], 0, 0, 0);
      acc[rs][1] = __builtin_amdgcn_mfma_f32_16x16x32_bf16(af, bf1, acc[rs][1], 0, 0, 0);
      acc[rs][2] = __builtin_amdgcn_mfma_f32_16x16x32_bf16(af, bf2, acc[rs][2], 0, 0, 0);
      acc[rs][3] = __builtin_amdgcn_mfma_f32_16x16x32_bf16(af, bf3, acc[rs][3], 0, 0, 0);
    }
  }
  __syncthreads();
  gemm_epilogue<true, false>(acc, (char*)mw, bias, Hout, nullptr, b, it);
}

// ---------- k_g3: union-plane gemm + pool3 + last-arriver tail ---------------
__global__ __launch_bounds__(512) void k_g3(
    const unsigned* __restrict__ UP, const unsigned short* __restrict__ xws,
    const float* __restrict__ bias, float* __restrict__ PART3,
    const float* __restrict__ PP1, const float* __restrict__ PP2,
    const float* __restrict__ w_map, const float* __restrict__ b_map,
    float* __restrict__ out, unsigned* __restrict__ CNT) {
  __shared__ __align__(16) unsigned mw[4096];
  __shared__ unsigned lastf;
  const int bid = blockIdx.x, tid = threadIdx.x;
  const int b = bid & 7, it = bid >> 3;
  const int wave = tid >> 6, lane = tid & 63;
  const int m = lane & 15, kq = lane >> 4;
  const int i0 = it * 64;
  for (int idx = tid; idx < 4096; idx += 512) {
    int row = idx >> 6, w = idx & 63;
    mw[row * 64 + (w ^ (row & 31))] = UP[((long)b * NN + i0 + row) * 64 + w];
  }
  __syncthreads();
  floatx4 acc[4][4];
#pragma unroll
  for (int rs = 0; rs < 4; ++rs)
#pragma unroll
    for (int t = 0; t < 4; ++t) acc[rs][t] = floatx4{0, 0, 0, 0};
  for (int kk8 = 0; kk8 < 8; ++kk8) {
    const int kblk = kk8 * 8 + wave;
    const unsigned short* bb = xws + ((long)b * 64 + kblk) * 2048 + lane * 8;
    short8 bf0 = *(const short8*)(bb);
    short8 bf1 = *(const short8*)(bb + 512);
    short8 bf2 = *(const short8*)(bb + 1024);
    short8 bf3 = *(const short8*)(bb + 1536);
#pragma unroll
    for (int rs = 0; rs < 4; ++rs) {
      const int row = rs * 16 + m;
      short8 af = expand_frag(mw[row * 64 + (kblk ^ (row & 31))], kq);
      acc[rs][0] = __builtin_amdgcn_mfma_f32_16x16x32_bf16(af, bf0, acc[rs][0], 0, 0, 0);
      acc[rs][1] = __builtin_amdgcn_mfma_f32_16x16x32_bf16(af, bf1, acc[rs][1], 0, 0, 0);
      acc[rs][2] = __builtin_amdgcn_mfma_f32_16x16x32_bf16(af, bf2, acc[rs][2], 0, 0, 0);
      acc[rs][3] = __builtin_amdgcn_mfma_f32_16x16x32_bf16(af, bf3, acc[rs][3], 0, 0, 0);
    }
  }
  __syncthreads();
  gemm_epilogue<false, true>(acc, (char*)mw, bias, nullptr, PART3, b, it);

  // last-arriver tail (R9-proven protocol; dirty L2 here is only PART3)
  __threadfence();
  __syncthreads();
  if (tid == 0) {
    unsigned r = __hip_atomic_fetch_add(CNT, 1u, __ATOMIC_ACQ_REL,
                                        __HIP_MEMORY_SCOPE_AGENT);
    lastf = (r == 255u) ? 1u : 0u;
  }
  __syncthreads();
  if (!lastf) return;
  __threadfence();
  const int bb = tid >> 6, e = tid & 63;
  float m1 = -3.4e38f, m2 = -3.4e38f, m3 = -3.4e38f;
#pragma unroll
  for (int c = 0; c < 32; ++c) {
    m1 = fmaxf(m1, PP1[(long)c * 512 + tid]);
    m2 = fmaxf(m2, PP2[(long)c * 512 + tid]);
    m3 = fmaxf(m3, PART3[((long)bb * 32 + c) * 64 + e]);
  }
  out[bb * 192 + e] = m1;
  out[bb * 192 + 64 + e] = m2;
  out[bb * 192 + 128 + e] = m3;
  __syncthreads();
  float a = b_map[e];
  for (int k = 0; k < 192; ++k) a += out[bb * 192 + k] * w_map[k * 64 + e];
  out[1536 + bb * 64 + e] = a;
}

// ---------- fused BN + xw_h (+pool partial from b==0 blocks) [R7-proven] -----
__global__ __launch_bounds__(256) void k_xwh_bn(const float* __restrict__ H,
                                                const float* __restrict__ w,
                                                unsigned short* __restrict__ xws,
                                                float* __restrict__ PP) {
  __shared__ float hs[64 * 65];
  __shared__ float wsh[64 * 64];
  __shared__ float sm[64], srs[64];
  const int bid = blockIdx.x, tid = threadIdx.x;
  const int jc = bid & 31, b = bid >> 5;
  const int j0 = jc * 64;
  {
    const int n = tid >> 2, q = tid & 3;
    float s1 = 0.f, s2 = 0.f;
#pragma unroll
    for (int bb = 0; bb < 8; ++bb) {
      const float4* hp =
          (const float4*)(H + ((long)bb * NN + j0 + n) * 64 + q * 16);
#pragma unroll
      for (int c = 0; c < 4; ++c) {
        float4 v = hp[c];
        s1 += v.x + v.y + v.z + v.w;
        s2 += v.x * v.x + v.y * v.y + v.z * v.z + v.w * v.w;
      }
    }
    s1 += __shfl_xor(s1, 1);
    s2 += __shfl_xor(s2, 1);
    s1 += __shfl_xor(s1, 2);
    s2 += __shfl_xor(s2, 2);
    if (q == 0) {
      float mean = s1 * (1.0f / 512.0f);
      float var = fmaxf(s2 * (1.0f / 512.0f) - mean * mean, 0.0f);
      sm[n] = mean;
      srs[n] = rsqrtf(var + 1e-5f);
    }
  }
  __syncthreads();
  for (int idx = tid; idx < 4096; idx += 256) {
    int row = idx >> 6, f = idx & 63;
    float v = H[((long)b * NN + j0 + row) * 64 + f];
    hs[row * 65 + f] = (v - sm[row]) * srs[row];
    wsh[idx] = w[idx];
  }
  __syncthreads();
  {
    const int j = tid & 63, g = tid >> 6;
    const int k = j0 + j;
    const int kblk = k >> 5, kq = (k >> 3) & 3, kj = k & 7;
    unsigned short* dst = xws + (((long)b * 64 + kblk) * 4 + g) * 512 + kj;
    float acc[16];
#pragma unroll
    for (int ii = 0; ii < 16; ++ii) acc[ii] = 0.f;
#pragma unroll
    for (int c = 0; c < 4; ++c) {
      float xr[16];
#pragma unroll
      for (int f = 0; f < 16; ++f) xr[f] = hs[j * 65 + c * 16 + f];
#pragma unroll
      for (int ii = 0; ii < 16; ++ii)
#pragma unroll
        for (int f = 0; f < 16; ++f)
          acc[ii] += xr[f] * wsh[(c * 16 + f) * 64 + g * 16 + ii];
    }
#pragma unroll
    for (int ii = 0; ii < 16; ++ii) dst[(kq * 16 + ii) * 8] = f2bf(acc[ii]);
  }
  if (b == 0) {
#pragma unroll
    for (int part = 0; part < 2; ++part) {
      const int col = part * 256 + tid;
      const int bb = col >> 6, e = col & 63;
      float mx = -3.4e38f;
      for (int n = 0; n < 64; ++n) {
        float v = H[((long)bb * NN + j0 + n) * 64 + e];
        mx = fmaxf(mx, (v - sm[n]) * srs[n]);
      }
      PP[(long)jc * 512 + col] = mx;
    }
  }
}

extern "C" void kernel_launch(void* const* d_in, const int* in_sizes, int n_in,
                              void* d_out, int out_size, void* d_ws,
                              size_t ws_size, hipStream_t stream) {
  const float* x = (const float*)d_in[0];
  const int* rel = (const int*)d_in[1];
  // d_in[2] (adj) unread: adj == (rel > 0) == union of bitplanes
  const float* w_first = (const float*)d_in[3];
  const float* b_first = (const float*)d_in[4];
  const float* w_block = (const float*)d_in[5];
  const float* b_block = (const float*)d_in[6];
  const float* w_last = (const float*)d_in[7];
  const float* b_last = (const float*)d_in[8];
  const float* w_map = (const float*)d_in[9];
  const float* b_map = (const float*)d_in[10];
  float* out = (float*)d_out;

  char* ws = (char*)d_ws;
  const size_t MB = 1024 * 1024;
  unsigned* UP = (unsigned*)(ws);                        // 4 MiB union plane
  unsigned short* XWS = (unsigned short*)(ws + 4 * MB);  // 6 MiB
  float* H = (float*)(ws + 12 * MB);                     // 4 MiB
  float* PP1 = (float*)(ws + 16 * MB);                   // 64 KiB
  float* PP2 = (float*)(ws + 17 * MB);                   // 64 KiB
  float* PART3 = (float*)(ws + 18 * MB);                 // 64 KiB
  unsigned* CNT = (unsigned*)(ws + 19 * MB);             // 4 B

  // ---- XW(layer1) + CNT zero ----
  k_xw1<<<768, 256, 0, stream>>>(x, w_first, XWS, CNT);
  // ---- layer 1: inline rel pack + gemm + fused epilogue; emits UP ----
  k_g1<<<256, 512, 0, stream>>>(rel, UP, XWS, b_first, H);
  k_xwh_bn<<<256, 256, 0, stream>>>(H, w_block, XWS, PP1);
  // ---- layer 2 ----
  k_gemm2<<<256, 512, 0, stream>>>(UP, XWS, b_block, H);
  k_xwh_bn<<<256, 256, 0, stream>>>(H, w_last, XWS, PP2);
  // ---- layer 3 + last-arriver tail ----
  k_g3<<<256, 512, 0, stream>>>(UP, XWS, b_last, PART3, PP1, PP2, w_map,
                                b_map, out, CNT);
}

// Round 12
// 384.644 us; speedup vs baseline: 1.0016x; 1.0016x over previous
//
#include <hip/hip_runtime.h>

// GcnEncoderGraph multi-kernel pipeline. B=8, N=2048, DIN=32, DH=DE=64, R=3.
// R12 = R11 with k_g1's ballot pack (78us: lane-0 ds_write serialization)
// replaced by the R10-proven thread-parallel byte pack (thread owns one
// 32-col word, 128B contiguous/lane, 8KB/wave), writing LDS planes + UP
// straight from registers. Everything else identical to R11/R10.
// Journal: no all-block rendezvous; single last-arriver fence round is OK;
// TLP >= 8 waves/CU for gemms; dispatch boundary = cheap sync (~10-15us).

#define NN 2048

typedef short short8 __attribute__((ext_vector_type(8)));
typedef float floatx4 __attribute__((ext_vector_type(4)));

__device__ __forceinline__ unsigned short f2bf(float x) {
  unsigned u = __float_as_uint(x);
  u += 0x7FFFu + ((u >> 16) & 1u);
  return (unsigned short)(u >> 16);
}

// ---------- shared epilogue: combine 8 waves, bias + L2norm (+relu/+pool) ----
template <bool RELU, bool POOL3>
__device__ __forceinline__ void gemm_epilogue(
    floatx4 acc[4][4], char* scratch, const float* __restrict__ bias,
    float* __restrict__ Hout, float* __restrict__ part3, int b, int it) {
  const int tid = threadIdx.x;
  const int wave = tid >> 6, lane = tid & 63;
  const int m = lane & 15, kq = lane >> 4;
  const int i0 = it * 64;
  floatx4* cb = (floatx4*)scratch;
  for (int k = 7; k >= 1; --k) {
    if (wave == k) {
      if (k == 7) {
#pragma unroll
        for (int rs = 0; rs < 4; ++rs)
#pragma unroll
          for (int t = 0; t < 4; ++t) cb[(rs * 4 + t) * 64 + lane] = acc[rs][t];
      } else {
#pragma unroll
        for (int rs = 0; rs < 4; ++rs)
#pragma unroll
          for (int t = 0; t < 4; ++t) {
            floatx4 v = cb[(rs * 4 + t) * 64 + lane];
            cb[(rs * 4 + t) * 64 + lane] = v + acc[rs][t];
          }
      }
    }
    __syncthreads();
  }
  if (wave == 0) {
#pragma unroll
    for (int rs = 0; rs < 4; ++rs)
#pragma unroll
      for (int t = 0; t < 4; ++t) acc[rs][t] += cb[(rs * 4 + t) * 64 + lane];
    float bv[4];
#pragma unroll
    for (int t = 0; t < 4; ++t) bv[t] = bias[t * 16 + m];
    float pmt[4] = {-3.4e38f, -3.4e38f, -3.4e38f, -3.4e38f};
#pragma unroll
    for (int rs = 0; rs < 4; ++rs) {
      float ss[4];
#pragma unroll
      for (int reg = 0; reg < 4; ++reg) {
#pragma unroll
        for (int t = 0; t < 4; ++t) acc[rs][t][reg] += bv[t];
        ss[reg] = acc[rs][0][reg] * acc[rs][0][reg] +
                  acc[rs][1][reg] * acc[rs][1][reg] +
                  acc[rs][2][reg] * acc[rs][2][reg] +
                  acc[rs][3][reg] * acc[rs][3][reg];
#pragma unroll
        for (int off = 1; off <= 8; off <<= 1)
          ss[reg] += __shfl_xor(ss[reg], off);
        ss[reg] = 1.0f / fmaxf(sqrtf(ss[reg]), 1e-12f);
      }
#pragma unroll
      for (int t = 0; t < 4; ++t) {
#pragma unroll
        for (int reg = 0; reg < 4; ++reg) {
          float o = acc[rs][t][reg] * ss[reg];
          if (RELU) o = fmaxf(o, 0.0f);
          if (POOL3)
            pmt[t] = fmaxf(pmt[t], o);
          else
            Hout[((long)b * NN + i0 + rs * 16 + kq * 4 + reg) * 64 + t * 16 + m] = o;
        }
      }
    }
    if (POOL3) {
#pragma unroll
      for (int t = 0; t < 4; ++t) {
        pmt[t] = fmaxf(pmt[t], __shfl_xor(pmt[t], 16));
        pmt[t] = fmaxf(pmt[t], __shfl_xor(pmt[t], 32));
      }
      if (kq == 0) {
#pragma unroll
        for (int t = 0; t < 4; ++t)
          part3[((long)b * 32 + it) * 64 + t * 16 + m] = pmt[t];
      }
    }
  }
}

// ---------- mask word -> bf16x8 A-fragment (u24-multiply expand, R10) --------
__device__ __forceinline__ short8 expand_frag(unsigned word, int kq) {
  unsigned byte = (word >> (kq * 8)) & 0xffu;
  unsigned pp = byte | (byte << 15);
  union {
    unsigned uu[4];
    short8 s8;
  } fr;
  fr.uu[0] = (pp & 0x00010001u) * 0x3F80u;
  fr.uu[1] = (pp & 0x00040004u) * 0x0FE0u;
  fr.uu[2] = (pp & 0x00100010u) * 0x03F8u;
  fr.uu[3] = (pp & 0x00400040u) * 0x00FEu;
  return fr.s8;
}

// ---------- k_xw1: XW layer1 (proven) + CNT zero -----------------------------
__global__ __launch_bounds__(256) void k_xw1(const float* __restrict__ x,
                                             const float* __restrict__ w,
                                             unsigned short* __restrict__ xws,
                                             unsigned* __restrict__ CNT) {
  __shared__ __align__(16) char smemc[16640];
  const int u = blockIdx.x, tid = threadIdx.x;
  if (u == 0 && tid == 0) CNT[0] = 0;  // consumed by k_g3, 4 dispatches later
  float* xs = (float*)smemc;                   // [64][33]
  float* wsh = (float*)(smemc + 64 * 33 * 4);  // [32][64]
  const int jc = u & 31, b = (u >> 5) & 7, r = u >> 8;
  const int j0 = jc * 64;
  for (int idx = tid; idx < 64 * 32; idx += 256) {
    int row = idx >> 5, f = idx & 31;
    xs[row * 33 + f] = x[((long)b * NN + j0 + row) * 32 + f];
    wsh[idx] = w[r * 2048 + idx];
  }
  __syncthreads();
  const int j = tid & 63, g = tid >> 6;
  const int k = j0 + j;
  const int kblk = k >> 5, kq = (k >> 3) & 3, kj = k & 7;
  unsigned short* dst =
      xws + (((long)(r * 8 + b) * 64 + kblk) * 4 + g) * 512 + kj;
  float xr[32];
#pragma unroll
  for (int f = 0; f < 32; ++f) xr[f] = xs[j * 33 + f];
#pragma unroll
  for (int ii = 0; ii < 16; ++ii) {
    float acc = 0.f;
#pragma unroll
    for (int f = 0; f < 32; ++f) acc += xr[f] * wsh[f * 64 + g * 16 + ii];
    dst[(kq * 16 + ii) * 8] = f2bf(acc);
  }
}

// ---------- k_g1: thread-parallel pack rel -> LDS + UP; gemm<3>; epilogue ----
// grid 256: b = bid&7, it = bid>>3. Block 512 = 8 waves. LDS: 3x16KB planes
// (word w of row at row*64 + (w^(row&31))); combine buffer overlays plane 0.
__global__ __launch_bounds__(512) void k_g1(
    const int* __restrict__ rel, unsigned* __restrict__ UP,
    const unsigned short* __restrict__ xws, const float* __restrict__ bias,
    float* __restrict__ Hout) {
  __shared__ __align__(16) unsigned mw[3 * 4096];
  const int bid = blockIdx.x, tid = threadIdx.x;
  const int b = bid & 7, it = bid >> 3;
  const int wave = tid >> 6, lane = tid & 63;
  const int i0 = it * 64;

  // ---- pack: thread owns word (row = u*8+wave, w = lane); 128B/lane,
  //      8KB contiguous per wave per u-step (R10 pack addressing, LDS dest)
  for (int u = 0; u < 8; ++u) {
    const int row = u * 8 + wave;
    const int w = lane;
    const int4* rp = (const int4*)(rel + ((long)b * NN + i0 + row) * NN + w * 32);
    unsigned m0 = 0, m1 = 0, m2 = 0;
#pragma unroll
    for (int c = 0; c < 8; ++c) {
      int4 v = rp[c];
      int vv[4] = {v.x, v.y, v.z, v.w};
#pragma unroll
      for (int q = 0; q < 4; ++q) {
        unsigned bit = 1u << (c * 4 + q);
        m0 |= (vv[q] == 1) ? bit : 0u;
        m1 |= (vv[q] == 2) ? bit : 0u;
        m2 |= (vv[q] == 3) ? bit : 0u;
      }
    }
    const int off = row * 64 + (w ^ (row & 31));
    mw[off] = m0;
    mw[4096 + off] = m1;
    mw[8192 + off] = m2;
    UP[((long)b * NN + i0 + row) * 64 + w] = m0 | m1 | m2;  // from registers
  }
  __syncthreads();

  // ---- gemm: 8 waves interleave K (kblk = kk8*8+wave), full K from LDS
  const int m = lane & 15, kq = lane >> 4;
  floatx4 acc[4][4];
#pragma unroll
  for (int rs = 0; rs < 4; ++rs)
#pragma unroll
    for (int t = 0; t < 4; ++t) acc[rs][t] = floatx4{0, 0, 0, 0};

  for (int kk8 = 0; kk8 < 8; ++kk8) {
    const int kblk = kk8 * 8 + wave;
#pragma unroll
    for (int p = 0; p < 3; ++p) {
      const unsigned short* bb =
          xws + ((long)(p * 8 + b) * 64 + kblk) * 2048 + lane * 8;
      short8 bf0 = *(const short8*)(bb);
      short8 bf1 = *(const short8*)(bb + 512);
      short8 bf2 = *(const short8*)(bb + 1024);
      short8 bf3 = *(const short8*)(bb + 1536);
#pragma unroll
      for (int rs = 0; rs < 4; ++rs) {
        const int row = rs * 16 + m;
        short8 af = expand_frag(mw[p * 4096 + row * 64 + (kblk ^ (row & 31))], kq);
        acc[rs][0] = __builtin_amdgcn_mfma_f32_16x16x32_bf16(af, bf0, acc[rs][0], 0, 0, 0);
        acc[rs][1] = __builtin_amdgcn_mfma_f32_16x16x32_bf16(af, bf1, acc[rs][1], 0, 0, 0);
        acc[rs][2] = __builtin_amdgcn_mfma_f32_16x16x32_bf16(af, bf2, acc[rs][2], 0, 0, 0);
        acc[rs][3] = __builtin_amdgcn_mfma_f32_16x16x32_bf16(af, bf3, acc[rs][3], 0, 0, 0);
      }
    }
  }
  __syncthreads();  // masks dead; LDS becomes combine buffer
  gemm_epilogue<true, false>(acc, (char*)mw, bias, Hout, nullptr, b, it);
}

// ---------- k_gemm2: union-plane gemm (proven) -------------------------------
__global__ __launch_bounds__(512) void k_gemm2(
    const unsigned* __restrict__ UP, const unsigned short* __restrict__ xws,
    const float* __restrict__ bias, float* __restrict__ Hout) {
  __shared__ __align__(16) unsigned mw[4096];
  const int bid = blockIdx.x, tid = threadIdx.x;
  const int b = bid & 7, it = bid >> 3;
  const int wave = tid >> 6, lane = tid & 63;
  const int m = lane & 15, kq = lane >> 4;
  const int i0 = it * 64;
  for (int idx = tid; idx < 4096; idx += 512) {
    int row = idx >> 6, w = idx & 63;
    mw[row * 64 + (w ^ (row & 31))] = UP[((long)b * NN + i0 + row) * 64 + w];
  }
  __syncthreads();
  floatx4 acc[4][4];
#pragma unroll
  for (int rs = 0; rs < 4; ++rs)
#pragma unroll
    for (int t = 0; t < 4; ++t) acc[rs][t] = floatx4{0, 0, 0, 0};
  for (int kk8 = 0; kk8 < 8; ++kk8) {
    const int kblk = kk8 * 8 + wave;
    const unsigned short* bb = xws + ((long)b * 64 + kblk) * 2048 + lane * 8;
    short8 bf0 = *(const short8*)(bb);
    short8 bf1 = *(const short8*)(bb + 512);
    short8 bf2 = *(const short8*)(bb + 1024);
    short8 bf3 = *(const short8*)(bb + 1536);
#pragma unroll
    for (int rs = 0; rs < 4; ++rs) {
      const int row = rs * 16 + m;
      short8 af = expand_frag(mw[row * 64 + (kblk ^ (row & 31))], kq);
      acc[rs][0] = __builtin_amdgcn_mfma_f32_16x16x32_bf16(af, bf0, acc[rs][0], 0, 0, 0);
      acc[rs][1] = __builtin_amdgcn_mfma_f32_16x16x32_bf16(af, bf1, acc[rs][1], 0, 0, 0);
      acc[rs][2] = __builtin_amdgcn_mfma_f32_16x16x32_bf16(af, bf2, acc[rs][2], 0, 0, 0);
      acc[rs][3] = __builtin_amdgcn_mfma_f32_16x16x32_bf16(af, bf3, acc[rs][3], 0, 0, 0);
    }
  }
  __syncthreads();
  gemm_epilogue<true, false>(acc, (char*)mw, bias, Hout, nullptr, b, it);
}

// ---------- k_g3: union-plane gemm + pool3 + last-arriver tail ---------------
__global__ __launch_bounds__(512) void k_g3(
    const unsigned* __restrict__ UP, const unsigned short* __restrict__ xws,
    const float* __restrict__ bias, float* __restrict__ PART3,
    const float* __restrict__ PP1, const float* __restrict__ PP2,
    const float* __restrict__ w_map, const float* __restrict__ b_map,
    float* __restrict__ out, unsigned* __restrict__ CNT) {
  __shared__ __align__(16) unsigned mw[4096];
  __shared__ unsigned lastf;
  const int bid = blockIdx.x, tid = threadIdx.x;
  const int b = bid & 7, it = bid >> 3;
  const int wave = tid >> 6, lane = tid & 63;
  const int m = lane & 15, kq = lane >> 4;
  const int i0 = it * 64;
  for (int idx = tid; idx < 4096; idx += 512) {
    int row = idx >> 6, w = idx & 63;
    mw[row * 64 + (w ^ (row & 31))] = UP[((long)b * NN + i0 + row) * 64 + w];
  }
  __syncthreads();
  floatx4 acc[4][4];
#pragma unroll
  for (int rs = 0; rs < 4; ++rs)
#pragma unroll
    for (int t = 0; t < 4; ++t) acc[rs][t] = floatx4{0, 0, 0, 0};
  for (int kk8 = 0; kk8 < 8; ++kk8) {
    const int kblk = kk8 * 8 + wave;
    const unsigned short* bb = xws + ((long)b * 64 + kblk) * 2048 + lane * 8;
    short8 bf0 = *(const short8*)(bb);
    short8 bf1 = *(const short8*)(bb + 512);
    short8 bf2 = *(const short8*)(bb + 1024);
    short8 bf3 = *(const short8*)(bb + 1536);
#pragma unroll
    for (int rs = 0; rs < 4; ++rs) {
      const int row = rs * 16 + m;
      short8 af = expand_frag(mw[row * 64 + (kblk ^ (row & 31))], kq);
      acc[rs][0] = __builtin_amdgcn_mfma_f32_16x16x32_bf16(af, bf0, acc[rs][0], 0, 0, 0);
      acc[rs][1] = __builtin_amdgcn_mfma_f32_16x16x32_bf16(af, bf1, acc[rs][1], 0, 0, 0);
      acc[rs][2] = __builtin_amdgcn_mfma_f32_16x16x32_bf16(af, bf2, acc[rs][2], 0, 0, 0);
      acc[rs][3] = __builtin_amdgcn_mfma_f32_16x16x32_bf16(af, bf3, acc[rs][3], 0, 0, 0);
    }
  }
  __syncthreads();
  gemm_epilogue<false, true>(acc, (char*)mw, bias, nullptr, PART3, b, it);

  // last-arriver tail (single fence round — measured OK in R11)
  __threadfence();
  __syncthreads();
  if (tid == 0) {
    unsigned r = __hip_atomic_fetch_add(CNT, 1u, __ATOMIC_ACQ_REL,
                                        __HIP_MEMORY_SCOPE_AGENT);
    lastf = (r == 255u) ? 1u : 0u;
  }
  __syncthreads();
  if (!lastf) return;
  __threadfence();
  const int bb = tid >> 6, e = tid & 63;
  float m1 = -3.4e38f, m2 = -3.4e38f, m3 = -3.4e38f;
#pragma unroll
  for (int c = 0; c < 32; ++c) {
    m1 = fmaxf(m1, PP1[(long)c * 512 + tid]);
    m2 = fmaxf(m2, PP2[(long)c * 512 + tid]);
    m3 = fmaxf(m3, PART3[((long)bb * 32 + c) * 64 + e]);
  }
  out[bb * 192 + e] = m1;
  out[bb * 192 + 64 + e] = m2;
  out[bb * 192 + 128 + e] = m3;
  __syncthreads();
  float a = b_map[e];
  for (int k = 0; k < 192; ++k) a += out[bb * 192 + k] * w_map[k * 64 + e];
  out[1536 + bb * 64 + e] = a;
}

// ---------- fused BN + xw_h (+pool partial from b==0 blocks) [proven] --------
__global__ __launch_bounds__(256) void k_xwh_bn(const float* __restrict__ H,
                                                const float* __restrict__ w,
                                                unsigned short* __restrict__ xws,
                                                float* __restrict__ PP) {
  __shared__ float hs[64 * 65];
  __shared__ float wsh[64 * 64];
  __shared__ float sm[64], srs[64];
  const int bid = blockIdx.x, tid = threadIdx.x;
  const int jc = bid & 31, b = bid >> 5;
  const int j0 = jc * 64;
  {
    const int n = tid >> 2, q = tid & 3;
    float s1 = 0.f, s2 = 0.f;
#pragma unroll
    for (int bb = 0; bb < 8; ++bb) {
      const float4* hp =
          (const float4*)(H + ((long)bb * NN + j0 + n) * 64 + q * 16);
#pragma unroll
      for (int c = 0; c < 4; ++c) {
        float4 v = hp[c];
        s1 += v.x + v.y + v.z + v.w;
        s2 += v.x * v.x + v.y * v.y + v.z * v.z + v.w * v.w;
      }
    }
    s1 += __shfl_xor(s1, 1);
    s2 += __shfl_xor(s2, 1);
    s1 += __shfl_xor(s1, 2);
    s2 += __shfl_xor(s2, 2);
    if (q == 0) {
      float mean = s1 * (1.0f / 512.0f);
      float var = fmaxf(s2 * (1.0f / 512.0f) - mean * mean, 0.0f);
      sm[n] = mean;
      srs[n] = rsqrtf(var + 1e-5f);
    }
  }
  __syncthreads();
  for (int idx = tid; idx < 4096; idx += 256) {
    int row = idx >> 6, f = idx & 63;
    float v = H[((long)b * NN + j0 + row) * 64 + f];
    hs[row * 65 + f] = (v - sm[row]) * srs[row];
    wsh[idx] = w[idx];
  }
  __syncthreads();
  {
    const int j = tid & 63, g = tid >> 6;
    const int k = j0 + j;
    const int kblk = k >> 5, kq = (k >> 3) & 3, kj = k & 7;
    unsigned short* dst = xws + (((long)b * 64 + kblk) * 4 + g) * 512 + kj;
    float acc[16];
#pragma unroll
    for (int ii = 0; ii < 16; ++ii) acc[ii] = 0.f;
#pragma unroll
    for (int c = 0; c < 4; ++c) {
      float xr[16];
#pragma unroll
      for (int f = 0; f < 16; ++f) xr[f] = hs[j * 65 + c * 16 + f];
#pragma unroll
      for (int ii = 0; ii < 16; ++ii)
#pragma unroll
        for (int f = 0; f < 16; ++f)
          acc[ii] += xr[f] * wsh[(c * 16 + f) * 64 + g * 16 + ii];
    }
#pragma unroll
    for (int ii = 0; ii < 16; ++ii) dst[(kq * 16 + ii) * 8] = f2bf(acc[ii]);
  }
  if (b == 0) {
#pragma unroll
    for (int part = 0; part < 2; ++part) {
      const int col = part * 256 + tid;
      const int bb = col >> 6, e = col & 63;
      float mx = -3.4e38f;
      for (int n = 0; n < 64; ++n) {
        float v = H[((long)bb * NN + j0 + n) * 64 + e];
        mx = fmaxf(mx, (v - sm[n]) * srs[n]);
      }
      PP[(long)jc * 512 + col] = mx;
    }
  }
}

extern "C" void kernel_launch(void* const* d_in, const int* in_sizes, int n_in,
                              void* d_out, int out_size, void* d_ws,
                              size_t ws_size, hipStream_t stream) {
  const float* x = (const float*)d_in[0];
  const int* rel = (const int*)d_in[1];
  // d_in[2] (adj) unread: adj == (rel > 0) == union of bitplanes
  const float* w_first = (const float*)d_in[3];
  const float* b_first = (const float*)d_in[4];
  const float* w_block = (const float*)d_in[5];
  const float* b_block = (const float*)d_in[6];
  const float* w_last = (const float*)d_in[7];
  const float* b_last = (const float*)d_in[8];
  const float* w_map = (const float*)d_in[9];
  const float* b_map = (const float*)d_in[10];
  float* out = (float*)d_out;

  char* ws = (char*)d_ws;
  const size_t MB = 1024 * 1024;
  unsigned* UP = (unsigned*)(ws);                        // 4 MiB union plane
  unsigned short* XWS = (unsigned short*)(ws + 4 * MB);  // 6 MiB
  float* H = (float*)(ws + 12 * MB);                     // 4 MiB
  float* PP1 = (float*)(ws + 16 * MB);                   // 64 KiB
  float* PP2 = (float*)(ws + 17 * MB);                   // 64 KiB
  float* PART3 = (float*)(ws + 18 * MB);                 // 64 KiB
  unsigned* CNT = (unsigned*)(ws + 19 * MB);             // 4 B

  // ---- XW(layer1) + CNT zero ----
  k_xw1<<<768, 256, 0, stream>>>(x, w_first, XWS, CNT);
  // ---- layer 1: inline rel pack + gemm + fused epilogue; emits UP ----
  k_g1<<<256, 512, 0, stream>>>(rel, UP, XWS, b_first, H);
  k_xwh_bn<<<256, 256, 0, stream>>>(H, w_block, XWS, PP1);
  // ---- layer 2 ----
  k_gemm2<<<256, 512, 0, stream>>>(UP, XWS, b_block, H);
  k_xwh_bn<<<256, 256, 0, stream>>>(H, w_last, XWS, PP2);
  // ---- layer 3 + last-arriver tail ----
  k_g3<<<256, 512, 0, stream>>>(UP, XWS, b_last, PART3, PP1, PP2, w_map,
                                b_map, out, CNT);
}